// Round 3
// baseline (185.600 us; speedup 1.0000x reference)
//
#include <hip/hip_runtime.h>

#define Nn 1024
#define Ee 65536
#define Pq 1024
#define Din 128
#define Hh 64

// ---------------- degree / norm ----------------
__global__ void k_deg(const int* __restrict__ ei, float* __restrict__ deg) {
    int e = blockIdx.x * blockDim.x + threadIdx.x;
    if (e < Ee) atomicAdd(&deg[ei[Ee + e]], 1.0f);
}

__global__ void k_dinv(const float* __restrict__ deg, float* __restrict__ dinv) {
    int i = blockIdx.x * blockDim.x + threadIdx.x;
    if (i < Nn) dinv[i] = rsqrtf(deg[i] + 1.0f);
}

// ---------------- xw = X @ W  (X:[Nn,K], W:[K,64]) ----------------
template <int K>
__global__ void k_xw(const float* __restrict__ X, const float* __restrict__ W,
                     float* __restrict__ xw) {
    int gid = blockIdx.x * blockDim.x + threadIdx.x;  // Nn*64 threads
    int r = gid >> 6, c = gid & 63;
    float acc = 0.f;
    #pragma unroll 8
    for (int j = 0; j < K; ++j) acc += X[r * K + j] * W[j * 64 + c];
    xw[gid] = acc;
}

// ---------------- GCN scatter: out[col] += xw[row]*dinv[row]*dinv[col] ----------------
__global__ void k_scatter(const int* __restrict__ ei, const float* __restrict__ xw,
                          const float* __restrict__ dinv, float* __restrict__ out) {
    int gid = blockIdx.x * blockDim.x + threadIdx.x;  // Ee*64 threads
    int e = gid >> 6, c = gid & 63;
    int r = ei[e], cl = ei[Ee + e];
    atomicAdd(&out[cl * 64 + c], xw[r * 64 + c] * dinv[r] * dinv[cl]);
}

// ---------------- self-loop message + bias ----------------
__global__ void k_selfloop(float* __restrict__ out, const float* __restrict__ xw,
                           const float* __restrict__ dinv, const float* __restrict__ b) {
    int gid = blockIdx.x * blockDim.x + threadIdx.x;  // Nn*64
    int n = gid >> 6, c = gid & 63;
    float di = dinv[n];
    out[gid] += xw[gid] * di * di + b[c];
}

// ---------------- edge-index maps (last-edge-wins == max id; dup edges have equal values) ----------------
__global__ void k_buildM(const int* __restrict__ ei, int* __restrict__ M, int* __restrict__ MT) {
    int e = blockIdx.x * blockDim.x + threadIdx.x;
    if (e < Ee) {
        int r = ei[e], cl = ei[Ee + e];
        atomicMax(&M[r * Nn + cl], e);
        atomicMax(&MT[cl * Nn + r], e);
    }
}

// ---------------- one MLP head for 64 edges (lane = edge), output to swizzled LDS tile ----------------
__device__ __forceinline__ void mlp_head(const float4* __restrict__ hr,
                                         const float4* __restrict__ hc,
                                         const float* __restrict__ W,
                                         const float* __restrict__ b,
                                         const float* __restrict__ g,
                                         const float* __restrict__ be,
                                         float* __restrict__ tl, int lane) {
    float acc[64];
    #pragma unroll
    for (int c = 0; c < 64; ++c) acc[c] = b[c];
    // K-chunked: 16 xe values at a time keeps VGPR pressure low and lets
    // loads overlap the FMA stream. W reads are lane-uniform -> s_load.
    #pragma unroll
    for (int jc = 0; jc < 4; ++jc) {
        float4 a[4], v[4];
        #pragma unroll
        for (int k = 0; k < 4; ++k) { a[k] = hr[jc * 4 + k]; v[k] = hc[jc * 4 + k]; }
        float xe[16];
        #pragma unroll
        for (int k = 0; k < 4; ++k) {
            xe[4 * k + 0] = a[k].x * v[k].x;
            xe[4 * k + 1] = a[k].y * v[k].y;
            xe[4 * k + 2] = a[k].z * v[k].z;
            xe[4 * k + 3] = a[k].w * v[k].w;
        }
        #pragma unroll
        for (int j = 0; j < 16; ++j) {
            float xj = xe[j];
            const float* Wr = W + (jc * 16 + j) * 64;
            #pragma unroll
            for (int c = 0; c < 64; ++c) acc[c] = fmaf(xj, Wr[c], acc[c]);
        }
    }
    // lane-local LayerNorm
    float s0 = 0, s1 = 0, s2 = 0, s3 = 0, q0 = 0, q1 = 0, q2 = 0, q3 = 0;
    #pragma unroll
    for (int c = 0; c < 64; c += 4) {
        s0 += acc[c];     q0 += acc[c] * acc[c];
        s1 += acc[c + 1]; q1 += acc[c + 1] * acc[c + 1];
        s2 += acc[c + 2]; q2 += acc[c + 2] * acc[c + 2];
        s3 += acc[c + 3]; q3 += acc[c + 3] * acc[c + 3];
    }
    float s = (s0 + s1) + (s2 + s3);
    float q = (q0 + q1) + (q2 + q3);
    float mu = s * (1.f / 64.f);
    float var = q * (1.f / 64.f) - mu * mu;
    float rinv = rsqrtf(var + 1e-5f);
    // write row `lane` into LDS tile, group-swizzled: group gi -> gi ^ (lane&15)
    #pragma unroll
    for (int gi = 0; gi < 16; ++gi) {
        int gs = gi ^ (lane & 15);
        float4 ov;
        ov.x = fmaxf(0.f, (acc[4 * gi + 0] - mu) * rinv * g[4 * gi + 0] + be[4 * gi + 0]);
        ov.y = fmaxf(0.f, (acc[4 * gi + 1] - mu) * rinv * g[4 * gi + 1] + be[4 * gi + 1]);
        ov.z = fmaxf(0.f, (acc[4 * gi + 2] - mu) * rinv * g[4 * gi + 2] + be[4 * gi + 2]);
        ov.w = fmaxf(0.f, (acc[4 * gi + 3] - mu) * rinv * g[4 * gi + 3] + be[4 * gi + 3]);
        *(float4*)(tl + lane * 64 + gs * 4) = ov;
    }
}

// ---------------- per-edge MLP heads: wave = (edge-block half, head) ----------------
// 4 waves/block: waves {0,1} = heads {1,2} of edge block A, {2,3} = heads of block B.
// Compute lane=edge (scalar weights, lane-local LN), stage 64x64 f32 tile in
// swizzled LDS, then copy out with fully coalesced float4 stores.
__global__ __launch_bounds__(256, 2) void k_mlp_edges3(
    const int* __restrict__ ei, const float* __restrict__ h2,
    const float* __restrict__ W1, const float* __restrict__ b1,
    const float* __restrict__ g1, const float* __restrict__ be1,
    const float* __restrict__ W2, const float* __restrict__ b2,
    const float* __restrict__ g2, const float* __restrict__ be2,
    float* __restrict__ x1buf, float* __restrict__ x2buf) {
    __shared__ float tile[4][64 * 64];  // 64 KB
    int tid = threadIdx.x;
    int lane = tid & 63;
    int wv = tid >> 6;
    int half = wv >> 1, head = wv & 1;
    int ebase = (blockIdx.x * 2 + half) * 64;
    int e = ebase + lane;
    int r = ei[e], cl = ei[Ee + e];
    const float4* hr = (const float4*)(h2 + r * 64);
    const float4* hc = (const float4*)(h2 + cl * 64);
    float* tl = tile[wv];

    if (head == 0) mlp_head(hr, hc, W1, b1, g1, be1, tl, lane);
    else           mlp_head(hr, hc, W2, b2, g2, be2, tl, lane);

    // coalesced copy-out of this wave's 16 KB tile (no cross-wave sharing -> no barrier)
    float* buf = head ? x2buf : x1buf;
    float4* dst = (float4*)(buf + (size_t)ebase * 64);
    #pragma unroll
    for (int m = 0; m < 16; ++m) {
        int row = m * 4 + (lane >> 4);
        int gs = (lane & 15) ^ (row & 15);
        float4 vv = *(const float4*)(tl + row * 64 + gs * 4);
        dst[m * 64 + lane] = vv;
    }
}

// ---------------- xx pairs -> feat[:,64:128] ----------------
__global__ void k_xx(const int* __restrict__ pos, const float* __restrict__ h2,
                     float* __restrict__ feat) {
    int gid = blockIdx.x * blockDim.x + threadIdx.x;  // Pq*64
    int p = gid >> 6, c = gid & 63;
    feat[p * 128 + 64 + c] = h2[pos[p] * 64 + c] * h2[pos[Pq + p] * 64 + c];
}

// ---------------- pos_val[p,h] = sum_k x2[M[a,k]] * x1[MT[b,k]] -> feat[:,0:64] ----------------
__global__ __launch_bounds__(64) void k_posval(const int* __restrict__ pos,
                                               const int* __restrict__ M,
                                               const int* __restrict__ MT,
                                               const float* __restrict__ x1buf,
                                               const float* __restrict__ x2buf,
                                               float* __restrict__ feat) {
    int p = blockIdx.x;
    int lane = threadIdx.x;
    int a = pos[p], b = pos[Pq + p];
    float acc = 0.f;
    for (int k0 = 0; k0 < Nn; k0 += 64) {
        int m1 = M[a * Nn + k0 + lane];
        int m2 = MT[b * Nn + k0 + lane];
        unsigned long long mask = __ballot(m1 >= 0 && m2 >= 0);
        while (mask) {
            int i = __ffsll(mask) - 1;
            mask &= mask - 1;
            int e1 = __shfl(m1, i);
            int e2 = __shfl(m2, i);
            acc += x2buf[e1 * 64 + lane] * x1buf[e2 * 64 + lane];
        }
    }
    feat[p * 128 + lane] = acc;
}

// ---------------- final MLP: relu(feat@Wa+ba) @ Wb + bb ----------------
__global__ __launch_bounds__(256) void k_final(const float* __restrict__ feat,
                                               const float* __restrict__ Wa,
                                               const float* __restrict__ ba,
                                               const float* __restrict__ Wb,
                                               const float* __restrict__ bb,
                                               float* __restrict__ out) {
    int tid = threadIdx.x;
    int lane = tid & 63;
    int p = blockIdx.x * 4 + (tid >> 6);
    float f0 = feat[p * 128 + lane];
    float f1 = feat[p * 128 + 64 + lane];
    float acc = ba[lane];
    #pragma unroll 8
    for (int j = 0; j < 64; ++j) {
        acc += __shfl(f0, j) * Wa[j * 64 + lane];
        acc += __shfl(f1, j) * Wa[(64 + j) * 64 + lane];
    }
    acc = fmaxf(acc, 0.f);
    float v = acc * Wb[lane];
    for (int off = 32; off; off >>= 1) v += __shfl_xor(v, off);
    if (lane == 0) out[p] = v + bb[0];
}

extern "C" void kernel_launch(void* const* d_in, const int* in_sizes, int n_in,
                              void* d_out, int out_size, void* d_ws, size_t ws_size,
                              hipStream_t stream) {
    const float* x    = (const float*)d_in[0];
    const int*   ei   = (const int*)d_in[1];
    const int*   pos  = (const int*)d_in[2];
    const float* Wg1  = (const float*)d_in[3];
    const float* bg1  = (const float*)d_in[4];
    const float* Wg2  = (const float*)d_in[5];
    const float* bg2  = (const float*)d_in[6];
    const float* Wm1  = (const float*)d_in[7];
    const float* bm1  = (const float*)d_in[8];
    const float* gm1  = (const float*)d_in[9];
    const float* bem1 = (const float*)d_in[10];
    const float* Wm2  = (const float*)d_in[11];
    const float* bm2  = (const float*)d_in[12];
    const float* gm2  = (const float*)d_in[13];
    const float* bem2 = (const float*)d_in[14];
    const float* Wa   = (const float*)d_in[15];
    const float* ba   = (const float*)d_in[16];
    const float* Wb   = (const float*)d_in[17];
    const float* bb   = (const float*)d_in[18];
    float* out = (float*)d_out;

    char* w = (char*)d_ws;
    float* deg   = (float*)w;  w += 1024 * 4;
    float* dinv  = (float*)w;  w += 1024 * 4;
    float* xw    = (float*)w;  w += 65536 * 4;
    float* h1    = (float*)w;  w += 65536 * 4;
    float* h2    = (float*)w;  w += 65536 * 4;
    float* feat  = (float*)w;  w += (size_t)Pq * 128 * 4;
    float* x1buf = (float*)w;  w += (size_t)Ee * 64 * 4;
    float* x2buf = (float*)w;  w += (size_t)Ee * 64 * 4;
    int*   M     = (int*)w;    w += (size_t)Nn * Nn * 4;
    int*   MT    = (int*)w;    w += (size_t)Nn * Nn * 4;

    hipMemsetAsync(deg, 0, 1024 * 4, stream);
    hipMemsetAsync(h1, 0, 65536 * 4, stream);
    hipMemsetAsync(h2, 0, 65536 * 4, stream);
    hipMemsetAsync(M, 0xFF, (size_t)Nn * Nn * 4 * 2, stream);  // M and MT contiguous

    k_deg<<<Ee / 256, 256, 0, stream>>>(ei, deg);
    k_dinv<<<Nn / 256, 256, 0, stream>>>(deg, dinv);

    // GCN layer 1
    k_xw<Din><<<Nn * 64 / 256, 256, 0, stream>>>(x, Wg1, xw);
    k_scatter<<<(size_t)Ee * 64 / 256, 256, 0, stream>>>(ei, xw, dinv, h1);
    k_selfloop<<<Nn * 64 / 256, 256, 0, stream>>>(h1, xw, dinv, bg1);

    // GCN layer 2
    k_xw<Hh><<<Nn * 64 / 256, 256, 0, stream>>>(h1, Wg2, xw);
    k_scatter<<<(size_t)Ee * 64 / 256, 256, 0, stream>>>(ei, xw, dinv, h2);
    k_selfloop<<<Nn * 64 / 256, 256, 0, stream>>>(h2, xw, dinv, bg2);

    // edge maps + edge MLP heads
    k_buildM<<<Ee / 256, 256, 0, stream>>>(ei, M, MT);
    k_mlp_edges3<<<512, 256, 0, stream>>>(ei, h2, Wm1, bm1, gm1, bem1,
                                          Wm2, bm2, gm2, bem2, x1buf, x2buf);

    // features + bilinear sparse product
    k_xx<<<Pq * 64 / 256, 256, 0, stream>>>(pos, h2, feat);
    k_posval<<<Pq, 64, 0, stream>>>(pos, M, MT, x1buf, x2buf, feat);

    // final MLP
    k_final<<<Pq / 4, 256, 0, stream>>>(feat, Wa, ba, Wb, bb, out);
}

// Round 4
// 128.784 us; speedup vs baseline: 1.4412x; 1.4412x over previous
//
#include <hip/hip_runtime.h>

#define Nn 1024
#define Ee 65536
#define Pq 1024
#define Din 128
#define Hh 64

typedef __attribute__((ext_vector_type(4))) float f32x4;
typedef __attribute__((ext_vector_type(8))) short s16x8;

__device__ __forceinline__ unsigned short f2bf(float x) {
    unsigned b = __float_as_uint(x);
    unsigned r = (b + 0x7fffu + ((b >> 16) & 1u)) >> 16;
    return (unsigned short)r;
}
__device__ __forceinline__ float bf2f(unsigned short h) {
    return __uint_as_float(((unsigned)h) << 16);
}

// ---------------- degree / norm ----------------
__global__ void k_deg(const int* __restrict__ ei, float* __restrict__ deg) {
    int e = blockIdx.x * blockDim.x + threadIdx.x;
    if (e < Ee) atomicAdd(&deg[ei[Ee + e]], 1.0f);
}

__global__ void k_dinv(const float* __restrict__ deg, float* __restrict__ dinv) {
    int i = blockIdx.x * blockDim.x + threadIdx.x;
    if (i < Nn) dinv[i] = rsqrtf(deg[i] + 1.0f);
}

// ---------------- xw = X @ W  (X:[Nn,K], W:[K,64]) ----------------
template <int K>
__global__ void k_xw(const float* __restrict__ X, const float* __restrict__ W,
                     float* __restrict__ xw) {
    int gid = blockIdx.x * blockDim.x + threadIdx.x;  // Nn*64 threads
    int r = gid >> 6, c = gid & 63;
    float acc = 0.f;
    #pragma unroll 8
    for (int j = 0; j < K; ++j) acc += X[r * K + j] * W[j * 64 + c];
    xw[gid] = acc;
}

// ---------------- GCN scatter: out[col] += xw[row]*dinv[row]*dinv[col] ----------------
__global__ void k_scatter(const int* __restrict__ ei, const float* __restrict__ xw,
                          const float* __restrict__ dinv, float* __restrict__ out) {
    int gid = blockIdx.x * blockDim.x + threadIdx.x;  // Ee*64 threads
    int e = gid >> 6, c = gid & 63;
    int r = ei[e], cl = ei[Ee + e];
    atomicAdd(&out[cl * 64 + c], xw[r * 64 + c] * dinv[r] * dinv[cl]);
}

// ---------------- self-loop message + bias ----------------
__global__ void k_selfloop(float* __restrict__ out, const float* __restrict__ xw,
                           const float* __restrict__ dinv, const float* __restrict__ b) {
    int gid = blockIdx.x * blockDim.x + threadIdx.x;  // Nn*64
    int n = gid >> 6, c = gid & 63;
    float di = dinv[n];
    out[gid] += xw[gid] * di * di + b[c];
}

// ---------------- edge-index maps ----------------
__global__ void k_buildM(const int* __restrict__ ei, int* __restrict__ M, int* __restrict__ MT) {
    int e = blockIdx.x * blockDim.x + threadIdx.x;
    if (e < Ee) {
        int r = ei[e], cl = ei[Ee + e];
        atomicMax(&M[r * Nn + cl], e);
        atomicMax(&MT[cl * Nn + r], e);
    }
}

// ---------------- split W1|W2 into bf16 hi/lo MFMA B-fragments ----------------
// Frag f = nt*2+ks (nt: 8 col-tiles of 16, ks: 2 k-steps of 32).
// Lane l holds B[k = ks*32 + (l>>4)*8 + j][col = nt*16 + (l&15)], j=0..7.
// Stored flat: Wh/Wl[(f*64 + l)*8 + j].
__global__ void k_splitW(const float* __restrict__ W1, const float* __restrict__ W2,
                         unsigned short* __restrict__ Wh, unsigned short* __restrict__ Wl) {
    int t = threadIdx.x;
    int lane = t & 63;
    for (int f = t >> 6; f < 16; f += 4) {
        int nt = f >> 1, ks = f & 1;
        int col = nt * 16 + (lane & 15);
        #pragma unroll
        for (int j = 0; j < 8; ++j) {
            int k = ks * 32 + ((lane >> 4) << 3) + j;
            float wv = (col < 64) ? W1[k * 64 + col] : W2[k * 64 + (col - 64)];
            unsigned short hi = f2bf(wv);
            unsigned short lo = f2bf(wv - bf2f(hi));
            int idx = (f * 64 + lane) * 8 + j;
            Wh[idx] = hi;
            Wl[idx] = lo;
        }
    }
}

// ---------------- edge MLP via split-bf16 MFMA ----------------
// Block = 64 edges. 4 waves; wave w computes edges [w*16, w*16+16) x all 128 cols.
// xe staged in XOR-swizzled LDS (hi/lo bf16); per-wave f32 C-tile in LDS for
// bias + LayerNorm + ReLU epilogue; coalesced copy-out.
__global__ __launch_bounds__(256, 2) void k_mlp_mfma(
    const int* __restrict__ ei, const float* __restrict__ h2,
    const unsigned short* __restrict__ Wh, const unsigned short* __restrict__ Wl,
    const float* __restrict__ b1, const float* __restrict__ g1, const float* __restrict__ be1,
    const float* __restrict__ b2, const float* __restrict__ g2, const float* __restrict__ be2,
    float* __restrict__ x1buf, float* __restrict__ x2buf) {
    __shared__ unsigned int xeh[2048], xel[2048];  // [64 edges][64 k] bf16, kb-swizzled
    __shared__ float ctile[4][16 * 132];           // per-wave [16 rows][132] padded
    int tid = threadIdx.x;
    int lane = tid & 63;
    int w = tid >> 6;
    int eb = blockIdx.x * 64;

    // ---- stage xe hi/lo: thread = (edge = tid&63, k-chunk = tid>>6 of 16) ----
    {
        int e = tid & 63;
        int kc = tid >> 6;
        int r = ei[eb + e], cl = ei[Ee + eb + e];
        const float4* hr = (const float4*)(h2 + r * 64) + kc * 4;
        const float4* hc = (const float4*)(h2 + cl * 64) + kc * 4;
        float xe[16];
        #pragma unroll
        for (int i = 0; i < 4; ++i) {
            float4 a = hr[i], v = hc[i];
            xe[4 * i + 0] = a.x * v.x;
            xe[4 * i + 1] = a.y * v.y;
            xe[4 * i + 2] = a.z * v.z;
            xe[4 * i + 3] = a.w * v.w;
        }
        #pragma unroll
        for (int blk = 0; blk < 2; ++blk) {
            uint4 hw, lw;
            unsigned hv[4], lv[4];
            #pragma unroll
            for (int q = 0; q < 4; ++q) {
                float v0 = xe[blk * 8 + 2 * q], v1 = xe[blk * 8 + 2 * q + 1];
                unsigned short h0 = f2bf(v0), h1 = f2bf(v1);
                unsigned short l0 = f2bf(v0 - bf2f(h0)), l1 = f2bf(v1 - bf2f(h1));
                hv[q] = (unsigned)h0 | ((unsigned)h1 << 16);
                lv[q] = (unsigned)l0 | ((unsigned)l1 << 16);
            }
            hw.x = hv[0]; hw.y = hv[1]; hw.z = hv[2]; hw.w = hv[3];
            lw.x = lv[0]; lw.y = lv[1]; lw.z = lv[2]; lw.w = lv[3];
            int kb = kc * 2 + blk;
            int word = e * 32 + ((kb ^ (e & 7)) << 2);
            *(uint4*)(xeh + word) = hw;
            *(uint4*)(xel + word) = lw;
        }
    }
    __syncthreads();

    // ---- A fragments: row = w*16 + (lane&15), k = ks*32 + (lane>>4)*8 + j ----
    int erow = (w << 4) + (lane & 15);
    s16x8 ah[2], al[2];
    #pragma unroll
    for (int ks = 0; ks < 2; ++ks) {
        int kb = ks * 4 + (lane >> 4);
        int word = erow * 32 + ((kb ^ (erow & 7)) << 2);
        ah[ks] = *(const s16x8*)(xeh + word);
        al[ks] = *(const s16x8*)(xel + word);
    }

    // ---- MFMA: 8 col-tiles x 2 k-steps x 3 split-products ----
    float* ct = ctile[w];
    const s16x8* WhF = (const s16x8*)Wh;
    const s16x8* WlF = (const s16x8*)Wl;
    #pragma unroll
    for (int nt = 0; nt < 8; ++nt) {
        f32x4 c = {0.f, 0.f, 0.f, 0.f};
        #pragma unroll
        for (int ks = 0; ks < 2; ++ks) {
            s16x8 bh = WhF[(nt * 2 + ks) * 64 + lane];
            s16x8 bl = WlF[(nt * 2 + ks) * 64 + lane];
            c = __builtin_amdgcn_mfma_f32_16x16x32_bf16(ah[ks], bh, c, 0, 0, 0);
            c = __builtin_amdgcn_mfma_f32_16x16x32_bf16(ah[ks], bl, c, 0, 0, 0);
            c = __builtin_amdgcn_mfma_f32_16x16x32_bf16(al[ks], bh, c, 0, 0, 0);
        }
        // C frag: col = lane&15 (within tile), row = (lane>>4)*4 + r. Add bias here.
        int col = nt * 16 + (lane & 15);
        float bv = (col < 64) ? b1[col] : b2[col - 64];
        #pragma unroll
        for (int r2 = 0; r2 < 4; ++r2) {
            int row = ((lane >> 4) << 2) + r2;
            ct[row * 132 + col] = c[r2] + bv;
        }
    }
    // same-wave DS ordering guarantees visibility; no barrier needed (tile is per-wave)

    // ---- LayerNorm + ReLU: lane = (row = lane&15, col-block = (lane>>4)*32) ----
    {
        int row = lane & 15;
        int cb = (lane >> 4) << 5;         // 0,32,64,96
        int lb = cb & 63;                  // col base within head
        const float* gp  = (cb < 64) ? g1 : g2;
        const float* bep = (cb < 64) ? be1 : be2;
        float v[32];
        float s = 0.f, q = 0.f;
        #pragma unroll
        for (int k = 0; k < 32; ++k) {
            float x = ct[row * 132 + cb + k];
            v[k] = x;
            s += x;
            q += x * x;
        }
        s += __shfl_xor(s, 16);
        q += __shfl_xor(q, 16);
        float mu = s * (1.f / 64.f);
        float var = q * (1.f / 64.f) - mu * mu;
        float rinv = rsqrtf(var + 1e-5f);
        #pragma unroll
        for (int k = 0; k < 32; ++k) {
            float nv = fmaxf(0.f, (v[k] - mu) * rinv * gp[lb + k] + bep[lb + k]);
            ct[row * 132 + cb + k] = nv;
        }
    }

    // ---- coalesced copy-out: head0 -> x1buf, head1 -> x2buf ----
    int ebase = eb + w * 16;
    #pragma unroll
    for (int m = 0; m < 16; ++m) {
        float o0 = ct[m * 132 + lane];
        float o1 = ct[m * 132 + 64 + lane];
        x1buf[(size_t)(ebase + m) * 64 + lane] = o0;
        x2buf[(size_t)(ebase + m) * 64 + lane] = o1;
    }
}

// ---------------- xx pairs -> feat[:,64:128] ----------------
__global__ void k_xx(const int* __restrict__ pos, const float* __restrict__ h2,
                     float* __restrict__ feat) {
    int gid = blockIdx.x * blockDim.x + threadIdx.x;  // Pq*64
    int p = gid >> 6, c = gid & 63;
    feat[p * 128 + 64 + c] = h2[pos[p] * 64 + c] * h2[pos[Pq + p] * 64 + c];
}

// ---------------- pos_val[p,h] = sum_k x2[M[a,k]] * x1[MT[b,k]] -> feat[:,0:64] ----------------
__global__ __launch_bounds__(64) void k_posval(const int* __restrict__ pos,
                                               const int* __restrict__ M,
                                               const int* __restrict__ MT,
                                               const float* __restrict__ x1buf,
                                               const float* __restrict__ x2buf,
                                               float* __restrict__ feat) {
    int p = blockIdx.x;
    int lane = threadIdx.x;
    int a = pos[p], b = pos[Pq + p];
    float acc = 0.f;
    for (int k0 = 0; k0 < Nn; k0 += 64) {
        int m1 = M[a * Nn + k0 + lane];
        int m2 = MT[b * Nn + k0 + lane];
        unsigned long long mask = __ballot(m1 >= 0 && m2 >= 0);
        while (mask) {
            int i = __ffsll(mask) - 1;
            mask &= mask - 1;
            int e1 = __shfl(m1, i);
            int e2 = __shfl(m2, i);
            acc += x2buf[e1 * 64 + lane] * x1buf[e2 * 64 + lane];
        }
    }
    feat[p * 128 + lane] = acc;
}

// ---------------- final MLP: relu(feat@Wa+ba) @ Wb + bb ----------------
__global__ __launch_bounds__(256) void k_final(const float* __restrict__ feat,
                                               const float* __restrict__ Wa,
                                               const float* __restrict__ ba,
                                               const float* __restrict__ Wb,
                                               const float* __restrict__ bb,
                                               float* __restrict__ out) {
    int tid = threadIdx.x;
    int lane = tid & 63;
    int p = blockIdx.x * 4 + (tid >> 6);
    float f0 = feat[p * 128 + lane];
    float f1 = feat[p * 128 + 64 + lane];
    float acc = ba[lane];
    #pragma unroll 8
    for (int j = 0; j < 64; ++j) {
        acc += __shfl(f0, j) * Wa[j * 64 + lane];
        acc += __shfl(f1, j) * Wa[(64 + j) * 64 + lane];
    }
    acc = fmaxf(acc, 0.f);
    float v = acc * Wb[lane];
    for (int off = 32; off; off >>= 1) v += __shfl_xor(v, off);
    if (lane == 0) out[p] = v + bb[0];
}

extern "C" void kernel_launch(void* const* d_in, const int* in_sizes, int n_in,
                              void* d_out, int out_size, void* d_ws, size_t ws_size,
                              hipStream_t stream) {
    const float* x    = (const float*)d_in[0];
    const int*   ei   = (const int*)d_in[1];
    const int*   pos  = (const int*)d_in[2];
    const float* Wg1  = (const float*)d_in[3];
    const float* bg1  = (const float*)d_in[4];
    const float* Wg2  = (const float*)d_in[5];
    const float* bg2  = (const float*)d_in[6];
    const float* Wm1  = (const float*)d_in[7];
    const float* bm1  = (const float*)d_in[8];
    const float* gm1  = (const float*)d_in[9];
    const float* bem1 = (const float*)d_in[10];
    const float* Wm2  = (const float*)d_in[11];
    const float* bm2  = (const float*)d_in[12];
    const float* gm2  = (const float*)d_in[13];
    const float* bem2 = (const float*)d_in[14];
    const float* Wa   = (const float*)d_in[15];
    const float* ba   = (const float*)d_in[16];
    const float* Wb   = (const float*)d_in[17];
    const float* bb   = (const float*)d_in[18];
    float* out = (float*)d_out;

    char* w = (char*)d_ws;
    float* deg   = (float*)w;  w += 1024 * 4;
    float* dinv  = (float*)w;  w += 1024 * 4;
    float* xw    = (float*)w;  w += 65536 * 4;
    float* h1    = (float*)w;  w += 65536 * 4;
    float* h2    = (float*)w;  w += 65536 * 4;
    float* feat  = (float*)w;  w += (size_t)Pq * 128 * 4;
    float* x1buf = (float*)w;  w += (size_t)Ee * 64 * 4;
    float* x2buf = (float*)w;  w += (size_t)Ee * 64 * 4;
    int*   M     = (int*)w;    w += (size_t)Nn * Nn * 4;
    int*   MT    = (int*)w;    w += (size_t)Nn * Nn * 4;
    unsigned short* Whk = (unsigned short*)w;  w += 8192 * 2;
    unsigned short* Wlk = (unsigned short*)w;  w += 8192 * 2;

    hipMemsetAsync(deg, 0, 1024 * 4, stream);
    hipMemsetAsync(h1, 0, 65536 * 4, stream);
    hipMemsetAsync(h2, 0, 65536 * 4, stream);
    hipMemsetAsync(M, 0xFF, (size_t)Nn * Nn * 4 * 2, stream);  // M and MT contiguous

    k_splitW<<<1, 256, 0, stream>>>(Wm1, Wm2, Whk, Wlk);
    k_deg<<<Ee / 256, 256, 0, stream>>>(ei, deg);
    k_dinv<<<Nn / 256, 256, 0, stream>>>(deg, dinv);

    // GCN layer 1
    k_xw<Din><<<Nn * 64 / 256, 256, 0, stream>>>(x, Wg1, xw);
    k_scatter<<<(size_t)Ee * 64 / 256, 256, 0, stream>>>(ei, xw, dinv, h1);
    k_selfloop<<<Nn * 64 / 256, 256, 0, stream>>>(h1, xw, dinv, bg1);

    // GCN layer 2
    k_xw<Hh><<<Nn * 64 / 256, 256, 0, stream>>>(h1, Wg2, xw);
    k_scatter<<<(size_t)Ee * 64 / 256, 256, 0, stream>>>(ei, xw, dinv, h2);
    k_selfloop<<<Nn * 64 / 256, 256, 0, stream>>>(h2, xw, dinv, bg2);

    // edge maps + edge MLP heads (MFMA)
    k_buildM<<<Ee / 256, 256, 0, stream>>>(ei, M, MT);
    k_mlp_mfma<<<Ee / 64, 256, 0, stream>>>(ei, h2, Whk, Wlk,
                                            bm1, gm1, bem1, bm2, gm2, bem2,
                                            x1buf, x2buf);

    // features + bilinear sparse product
    k_xx<<<Pq * 64 / 256, 256, 0, stream>>>(pos, h2, feat);
    k_posval<<<Pq, 64, 0, stream>>>(pos, M, MT, x1buf, x2buf, feat);

    // final MLP
    k_final<<<Pq / 4, 256, 0, stream>>>(feat, Wa, ba, Wb, bb, out);
}

// Round 5
// 107.198 us; speedup vs baseline: 1.7314x; 1.2014x over previous
//
#include <hip/hip_runtime.h>

#define Nn 1024
#define Ee 65536
#define Pq 1024
#define Din 128
#define Hh 64

typedef __attribute__((ext_vector_type(4))) float f32x4;
typedef __attribute__((ext_vector_type(8))) short s16x8;

__device__ __forceinline__ unsigned short f2bf(float x) {
    unsigned b = __float_as_uint(x);
    unsigned r = (b + 0x7fffu + ((b >> 16) & 1u)) >> 16;
    return (unsigned short)r;
}
__device__ __forceinline__ float bf2f(unsigned short h) {
    return __uint_as_float(((unsigned)h) << 16);
}

// ---------------- single edge pass: deg, edge-id maps, presence bitmaps ----------------
__global__ void k_edgepass(const int* __restrict__ ei, int* __restrict__ degI,
                           int* __restrict__ M, int* __restrict__ MT,
                           unsigned long long* __restrict__ Mbit,
                           unsigned long long* __restrict__ MTbit) {
    int e = blockIdx.x * blockDim.x + threadIdx.x;
    if (e >= Ee) return;
    int r = ei[e], c = ei[Ee + e];
    atomicAdd(&degI[c], 1);
    atomicMax(&M[r * Nn + c], e);
    atomicMax(&MT[c * Nn + r], e);
    atomicOr(&Mbit[r * 16 + (c >> 6)], 1ull << (c & 63));
    atomicOr(&MTbit[c * 16 + (r >> 6)], 1ull << (r & 63));
}

// ---------------- scan: dst_start = exclusive prefix of deg; dinv ----------------
__global__ void k_scan(const int* __restrict__ degI, int* __restrict__ dst_start,
                       float* __restrict__ dinv) {
    __shared__ int s[1024];
    int t = threadIdx.x;
    int d = degI[t];
    s[t] = d;
    __syncthreads();
    for (int off = 1; off < 1024; off <<= 1) {
        int v = (t >= off) ? s[t - off] : 0;
        __syncthreads();
        s[t] += v;
        __syncthreads();
    }
    dst_start[t] = s[t] - d;
    dinv[t] = rsqrtf((float)d + 1.0f);
}

// ---------------- CSR placement (order within bucket nondeterministic; f32 sum tol ok) ----------------
__global__ void k_csr(const int* __restrict__ ei, const int* __restrict__ dst_start,
                      int* __restrict__ cursor, int* __restrict__ csr) {
    int e = blockIdx.x * blockDim.x + threadIdx.x;
    if (e >= Ee) return;
    int r = ei[e], c = ei[Ee + e];
    int slot = atomicAdd(&cursor[c], 1);
    csr[dst_start[c] + slot] = r;
}

// ---------------- xw = X @ W  (X:[Nn,K], W:[K,64]) ----------------
template <int K>
__global__ void k_xw(const float* __restrict__ X, const float* __restrict__ W,
                     float* __restrict__ xw) {
    int gid = blockIdx.x * blockDim.x + threadIdx.x;  // Nn*64 threads
    int r = gid >> 6, c = gid & 63;
    float acc = 0.f;
    #pragma unroll 8
    for (int j = 0; j < K; ++j) acc += X[r * K + j] * W[j * 64 + c];
    xw[gid] = acc;
}

// ---------------- GCN gather: h[c] = dinv_c * sum_e dinv_r*xw[r] + dinv_c^2*xw[c] + b ----------------
__global__ __launch_bounds__(256) void k_gather(const int* __restrict__ csr,
                                                const int* __restrict__ dst_start,
                                                const int* __restrict__ degI,
                                                const float* __restrict__ dinv,
                                                const float* __restrict__ xw,
                                                const float* __restrict__ b,
                                                float* __restrict__ h) {
    __shared__ float red[4][64];
    int c = blockIdx.x;
    int lane = threadIdx.x & 63;
    int w = threadIdx.x >> 6;
    int s0 = dst_start[c], n = degI[c];
    int j = s0 + w, end = s0 + n;
    float acc = 0.f;
    for (; j + 12 < end; j += 16) {  // 4-deep ILP within wave; waves interleave stride 4
        int r0 = csr[j], r1 = csr[j + 4], r2 = csr[j + 8], r3 = csr[j + 12];
        float d0 = dinv[r0], d1 = dinv[r1], d2 = dinv[r2], d3 = dinv[r3];
        acc += xw[r0 * 64 + lane] * d0;
        acc += xw[r1 * 64 + lane] * d1;
        acc += xw[r2 * 64 + lane] * d2;
        acc += xw[r3 * 64 + lane] * d3;
    }
    for (; j < end; j += 4) {
        int r = csr[j];
        acc += xw[r * 64 + lane] * dinv[r];
    }
    red[w][lane] = acc;
    __syncthreads();
    if (w == 0) {
        float a = (red[0][lane] + red[1][lane]) + (red[2][lane] + red[3][lane]);
        float dc = dinv[c];
        h[c * 64 + lane] = dc * a + dc * dc * xw[c * 64 + lane] + b[lane];
    }
}

// ---------------- split W1|W2 into bf16 hi/lo MFMA B-fragments ----------------
__global__ void k_splitW(const float* __restrict__ W1, const float* __restrict__ W2,
                         unsigned short* __restrict__ Wh, unsigned short* __restrict__ Wl) {
    int t = threadIdx.x;
    int lane = t & 63;
    for (int f = t >> 6; f < 16; f += 4) {
        int nt = f >> 1, ks = f & 1;
        int col = nt * 16 + (lane & 15);
        #pragma unroll
        for (int j = 0; j < 8; ++j) {
            int k = ks * 32 + ((lane >> 4) << 3) + j;
            float wv = (col < 64) ? W1[k * 64 + col] : W2[k * 64 + (col - 64)];
            unsigned short hi = f2bf(wv);
            unsigned short lo = f2bf(wv - bf2f(hi));
            int idx = (f * 64 + lane) * 8 + j;
            Wh[idx] = hi;
            Wl[idx] = lo;
        }
    }
}

// ---------------- edge MLP via split-bf16 MFMA (unchanged from R3, passed) ----------------
__global__ __launch_bounds__(256, 2) void k_mlp_mfma(
    const int* __restrict__ ei, const float* __restrict__ h2,
    const unsigned short* __restrict__ Wh, const unsigned short* __restrict__ Wl,
    const float* __restrict__ b1, const float* __restrict__ g1, const float* __restrict__ be1,
    const float* __restrict__ b2, const float* __restrict__ g2, const float* __restrict__ be2,
    float* __restrict__ x1buf, float* __restrict__ x2buf) {
    __shared__ unsigned int xeh[2048], xel[2048];  // [64 edges][64 k] bf16, kb-swizzled
    __shared__ float ctile[4][16 * 132];           // per-wave [16 rows][132] padded
    int tid = threadIdx.x;
    int lane = tid & 63;
    int w = tid >> 6;
    int eb = blockIdx.x * 64;

    {
        int e = tid & 63;
        int kc = tid >> 6;
        int r = ei[eb + e], cl = ei[Ee + eb + e];
        const float4* hr = (const float4*)(h2 + r * 64) + kc * 4;
        const float4* hc = (const float4*)(h2 + cl * 64) + kc * 4;
        float xe[16];
        #pragma unroll
        for (int i = 0; i < 4; ++i) {
            float4 a = hr[i], v = hc[i];
            xe[4 * i + 0] = a.x * v.x;
            xe[4 * i + 1] = a.y * v.y;
            xe[4 * i + 2] = a.z * v.z;
            xe[4 * i + 3] = a.w * v.w;
        }
        #pragma unroll
        for (int blk = 0; blk < 2; ++blk) {
            uint4 hw, lw;
            unsigned hv[4], lv[4];
            #pragma unroll
            for (int q = 0; q < 4; ++q) {
                float v0 = xe[blk * 8 + 2 * q], v1 = xe[blk * 8 + 2 * q + 1];
                unsigned short h0 = f2bf(v0), h1 = f2bf(v1);
                unsigned short l0 = f2bf(v0 - bf2f(h0)), l1 = f2bf(v1 - bf2f(h1));
                hv[q] = (unsigned)h0 | ((unsigned)h1 << 16);
                lv[q] = (unsigned)l0 | ((unsigned)l1 << 16);
            }
            hw.x = hv[0]; hw.y = hv[1]; hw.z = hv[2]; hw.w = hv[3];
            lw.x = lv[0]; lw.y = lv[1]; lw.z = lv[2]; lw.w = lv[3];
            int kb = kc * 2 + blk;
            int word = e * 32 + ((kb ^ (e & 7)) << 2);
            *(uint4*)(xeh + word) = hw;
            *(uint4*)(xel + word) = lw;
        }
    }
    __syncthreads();

    int erow = (w << 4) + (lane & 15);
    s16x8 ah[2], al[2];
    #pragma unroll
    for (int ks = 0; ks < 2; ++ks) {
        int kb = ks * 4 + (lane >> 4);
        int word = erow * 32 + ((kb ^ (erow & 7)) << 2);
        ah[ks] = *(const s16x8*)(xeh + word);
        al[ks] = *(const s16x8*)(xel + word);
    }

    float* ct = ctile[w];
    const s16x8* WhF = (const s16x8*)Wh;
    const s16x8* WlF = (const s16x8*)Wl;
    #pragma unroll
    for (int nt = 0; nt < 8; ++nt) {
        f32x4 c = {0.f, 0.f, 0.f, 0.f};
        #pragma unroll
        for (int ks = 0; ks < 2; ++ks) {
            s16x8 bh = WhF[(nt * 2 + ks) * 64 + lane];
            s16x8 bl = WlF[(nt * 2 + ks) * 64 + lane];
            c = __builtin_amdgcn_mfma_f32_16x16x32_bf16(ah[ks], bh, c, 0, 0, 0);
            c = __builtin_amdgcn_mfma_f32_16x16x32_bf16(ah[ks], bl, c, 0, 0, 0);
            c = __builtin_amdgcn_mfma_f32_16x16x32_bf16(al[ks], bh, c, 0, 0, 0);
        }
        int col = nt * 16 + (lane & 15);
        float bv = (col < 64) ? b1[col] : b2[col - 64];
        #pragma unroll
        for (int r2 = 0; r2 < 4; ++r2) {
            int row = ((lane >> 4) << 2) + r2;
            ct[row * 132 + col] = c[r2] + bv;
        }
    }

    {
        int row = lane & 15;
        int cb = (lane >> 4) << 5;
        int lb = cb & 63;
        const float* gp  = (cb < 64) ? g1 : g2;
        const float* bep = (cb < 64) ? be1 : be2;
        float v[32];
        float s = 0.f, q = 0.f;
        #pragma unroll
        for (int k = 0; k < 32; ++k) {
            float x = ct[row * 132 + cb + k];
            v[k] = x;
            s += x;
            q += x * x;
        }
        s += __shfl_xor(s, 16);
        q += __shfl_xor(q, 16);
        float mu = s * (1.f / 64.f);
        float var = q * (1.f / 64.f) - mu * mu;
        float rinv = rsqrtf(var + 1e-5f);
        #pragma unroll
        for (int k = 0; k < 32; ++k) {
            float nv = fmaxf(0.f, (v[k] - mu) * rinv * gp[lb + k] + bep[lb + k]);
            ct[row * 132 + cb + k] = nv;
        }
    }

    int ebase = eb + w * 16;
    #pragma unroll
    for (int m = 0; m < 16; ++m) {
        float o0 = ct[m * 132 + lane];
        float o1 = ct[m * 132 + 64 + lane];
        x1buf[(size_t)(ebase + m) * 64 + lane] = o0;
        x2buf[(size_t)(ebase + m) * 64 + lane] = o1;
    }
}

// ---------------- fused posval + xx + final MLP: wave = query ----------------
__global__ __launch_bounds__(256) void k_posfinal(
    const int* __restrict__ pos,
    const unsigned long long* __restrict__ Mbit, const unsigned long long* __restrict__ MTbit,
    const int* __restrict__ M, const int* __restrict__ MT,
    const float* __restrict__ x1buf, const float* __restrict__ x2buf,
    const float* __restrict__ h2,
    const float* __restrict__ Wa, const float* __restrict__ ba,
    const float* __restrict__ Wb, const float* __restrict__ bb,
    float* __restrict__ out) {
    int lane = threadIdx.x & 63;
    int w = threadIdx.x >> 6;
    int p = blockIdx.x * 4 + w;
    int a = pos[p], b = pos[Pq + p];
    a = __builtin_amdgcn_readfirstlane(a);
    b = __builtin_amdgcn_readfirstlane(b);
    float acc = 0.f;
    #pragma unroll 4
    for (int wd = 0; wd < 16; ++wd) {
        unsigned long long bits = Mbit[a * 16 + wd] & MTbit[b * 16 + wd];
        while (bits) {
            int k = (wd << 6) + __ffsll(bits) - 1;
            bits &= bits - 1;
            int e1 = __builtin_amdgcn_readfirstlane(M[a * Nn + k]);
            int e2 = __builtin_amdgcn_readfirstlane(MT[b * Nn + k]);
            acc += x2buf[(size_t)e1 * 64 + lane] * x1buf[(size_t)e2 * 64 + lane];
        }
    }
    float xx = h2[a * 64 + lane] * h2[b * 64 + lane];
    // final MLP
    float t = ba[lane];
    #pragma unroll 8
    for (int j = 0; j < 64; ++j) {
        t += __shfl(acc, j) * Wa[j * 64 + lane];
        t += __shfl(xx, j) * Wa[(64 + j) * 64 + lane];
    }
    t = fmaxf(t, 0.f);
    float v = t * Wb[lane];
    for (int off = 32; off; off >>= 1) v += __shfl_xor(v, off);
    if (lane == 0) out[p] = v + bb[0];
}

extern "C" void kernel_launch(void* const* d_in, const int* in_sizes, int n_in,
                              void* d_out, int out_size, void* d_ws, size_t ws_size,
                              hipStream_t stream) {
    const float* x    = (const float*)d_in[0];
    const int*   ei   = (const int*)d_in[1];
    const int*   pos  = (const int*)d_in[2];
    const float* Wg1  = (const float*)d_in[3];
    const float* bg1  = (const float*)d_in[4];
    const float* Wg2  = (const float*)d_in[5];
    const float* bg2  = (const float*)d_in[6];
    const float* Wm1  = (const float*)d_in[7];
    const float* bm1  = (const float*)d_in[8];
    const float* gm1  = (const float*)d_in[9];
    const float* bem1 = (const float*)d_in[10];
    const float* Wm2  = (const float*)d_in[11];
    const float* bm2  = (const float*)d_in[12];
    const float* gm2  = (const float*)d_in[13];
    const float* bem2 = (const float*)d_in[14];
    const float* Wa   = (const float*)d_in[15];
    const float* ba   = (const float*)d_in[16];
    const float* Wb   = (const float*)d_in[17];
    const float* bb   = (const float*)d_in[18];
    float* out = (float*)d_out;

    char* w = (char*)d_ws;
    // --- zero-init region (one memset) ---
    char* zbase = w;
    int* degI   = (int*)w;                 w += 1024 * 4;
    int* cursor = (int*)w;                 w += 1024 * 4;
    unsigned long long* Mbit  = (unsigned long long*)w;  w += 1024 * 16 * 8;
    unsigned long long* MTbit = (unsigned long long*)w;  w += 1024 * 16 * 8;
    size_t zbytes = (size_t)(w - zbase);
    // --- no-init ---
    int*   dst_start = (int*)w;    w += 1024 * 4;
    float* dinv  = (float*)w;      w += 1024 * 4;
    int*   csr   = (int*)w;        w += Ee * 4;
    float* xw    = (float*)w;      w += 65536 * 4;
    float* h1    = (float*)w;      w += 65536 * 4;
    float* h2    = (float*)w;      w += 65536 * 4;
    float* x1buf = (float*)w;      w += (size_t)Ee * 64 * 4;
    float* x2buf = (float*)w;      w += (size_t)Ee * 64 * 4;
    int*   M     = (int*)w;        w += (size_t)Nn * Nn * 4;
    int*   MT    = (int*)w;        w += (size_t)Nn * Nn * 4;
    unsigned short* Whk = (unsigned short*)w;  w += 8192 * 2;
    unsigned short* Wlk = (unsigned short*)w;  w += 8192 * 2;

    hipMemsetAsync(zbase, 0, zbytes, stream);
    hipMemsetAsync(M, 0xFF, (size_t)Nn * Nn * 4 * 2, stream);  // M and MT contiguous

    k_edgepass<<<Ee / 256, 256, 0, stream>>>(ei, degI, M, MT, Mbit, MTbit);
    k_scan<<<1, 1024, 0, stream>>>(degI, dst_start, dinv);
    k_csr<<<Ee / 256, 256, 0, stream>>>(ei, dst_start, cursor, csr);
    k_splitW<<<1, 256, 0, stream>>>(Wm1, Wm2, Whk, Wlk);

    // GCN layer 1
    k_xw<Din><<<Nn * 64 / 256, 256, 0, stream>>>(x, Wg1, xw);
    k_gather<<<Nn, 256, 0, stream>>>(csr, dst_start, degI, dinv, xw, bg1, h1);

    // GCN layer 2
    k_xw<Hh><<<Nn * 64 / 256, 256, 0, stream>>>(h1, Wg2, xw);
    k_gather<<<Nn, 256, 0, stream>>>(csr, dst_start, degI, dinv, xw, bg2, h2);

    // edge MLP heads (MFMA)
    k_mlp_mfma<<<Ee / 64, 256, 0, stream>>>(ei, h2, Whk, Wlk,
                                            bm1, gm1, bem1, bm2, gm2, bem2,
                                            x1buf, x2buf);

    // fused bilinear + xx + final MLP
    k_posfinal<<<Pq / 4, 256, 0, stream>>>(pos, Mbit, MTbit, M, MT,
                                           x1buf, x2buf, h2, Wa, ba, Wb, bb, out);
}

// Round 6
// 90.733 us; speedup vs baseline: 2.0456x; 1.1815x over previous
//
#include <hip/hip_runtime.h>

#define Nn 1024
#define Ee 65536
#define Pq 1024
#define Din 128
#define Hh 64

typedef unsigned long long ull;

// ---------------- single edge pass: deg + adjacency bitmaps ----------------
__global__ void k_edgepass(const int* __restrict__ ei, int* __restrict__ degI,
                           ull* __restrict__ Mbit, ull* __restrict__ MTbit) {
    int e = blockIdx.x * blockDim.x + threadIdx.x;
    if (e >= Ee) return;
    int r = ei[e], c = ei[Ee + e];
    atomicAdd(&degI[c], 1);
    atomicOr(&Mbit[r * 16 + (c >> 6)], 1ull << (c & 63));
    atomicOr(&MTbit[c * 16 + (r >> 6)], 1ull << (r & 63));
}

// ---------------- scan: dst_start = exclusive prefix of deg; dinv ----------------
__global__ void k_scan(const int* __restrict__ degI, int* __restrict__ dst_start,
                       float* __restrict__ dinv) {
    __shared__ int s[1024];
    int t = threadIdx.x;
    int d = degI[t];
    s[t] = d;
    __syncthreads();
    for (int off = 1; off < 1024; off <<= 1) {
        int v = (t >= off) ? s[t - off] : 0;
        __syncthreads();
        s[t] += v;
        __syncthreads();
    }
    dst_start[t] = s[t] - d;
    dinv[t] = rsqrtf((float)d + 1.0f);
}

// ---------------- CSR placement (order within bucket nondeterministic; f32 sum tol ok) ----------------
__global__ void k_csr(const int* __restrict__ ei, const int* __restrict__ dst_start,
                      int* __restrict__ cursor, int* __restrict__ csr) {
    int e = blockIdx.x * blockDim.x + threadIdx.x;
    if (e >= Ee) return;
    int r = ei[e], c = ei[Ee + e];
    int slot = atomicAdd(&cursor[c], 1);
    csr[dst_start[c] + slot] = r;
}

// ---------------- xw = X @ W  (X:[Nn,K], W:[K,64]) ----------------
template <int K>
__global__ void k_xw(const float* __restrict__ X, const float* __restrict__ W,
                     float* __restrict__ xw) {
    int gid = blockIdx.x * blockDim.x + threadIdx.x;  // Nn*64 threads
    int r = gid >> 6, c = gid & 63;
    float acc = 0.f;
    #pragma unroll 8
    for (int j = 0; j < K; ++j) acc += X[r * K + j] * W[j * 64 + c];
    xw[gid] = acc;
}

// ---------------- GCN gather: h[c] = dinv_c * sum_e dinv_r*xw[r] + dinv_c^2*xw[c] + b ----------------
__global__ __launch_bounds__(256) void k_gather(const int* __restrict__ csr,
                                                const int* __restrict__ dst_start,
                                                const int* __restrict__ degI,
                                                const float* __restrict__ dinv,
                                                const float* __restrict__ xw,
                                                const float* __restrict__ b,
                                                float* __restrict__ h) {
    __shared__ float red[4][64];
    int c = blockIdx.x;
    int lane = threadIdx.x & 63;
    int w = threadIdx.x >> 6;
    int s0 = dst_start[c], n = degI[c];
    int j = s0 + w, end = s0 + n;
    float acc = 0.f;
    for (; j + 12 < end; j += 16) {  // 4-deep ILP within wave; waves interleave stride 4
        int r0 = csr[j], r1 = csr[j + 4], r2 = csr[j + 8], r3 = csr[j + 12];
        float d0 = dinv[r0], d1 = dinv[r1], d2 = dinv[r2], d3 = dinv[r3];
        acc += xw[r0 * 64 + lane] * d0;
        acc += xw[r1 * 64 + lane] * d1;
        acc += xw[r2 * 64 + lane] * d2;
        acc += xw[r3 * 64 + lane] * d3;
    }
    for (; j < end; j += 4) {
        int r = csr[j];
        acc += xw[r * 64 + lane] * dinv[r];
    }
    red[w][lane] = acc;
    __syncthreads();
    if (w == 0) {
        float a = (red[0][lane] + red[1][lane]) + (red[2][lane] + red[3][lane]);
        float dc = dinv[c];
        h[c * 64 + lane] = dc * a + dc * dc * xw[c * 64 + lane] + b[lane];
    }
}

// ---------------- fused: bitmap intersect -> on-the-fly edge MLPs -> final MLP ----------------
// Wave = query. Per hit k: x2 = relu(LN(xe(a,k)@W2)), x1 = relu(LN(xe(k,b)@W1)),
// acc += x2*x1 (all f32, W1/W2 in LDS, shfl-broadcast matmul, wave-reduce LN).
__global__ __launch_bounds__(128) void k_posfinal(
    const int* __restrict__ pos,
    const ull* __restrict__ Mbit, const ull* __restrict__ MTbit,
    const float* __restrict__ h2,
    const float* __restrict__ W1, const float* __restrict__ b1,
    const float* __restrict__ g1, const float* __restrict__ be1,
    const float* __restrict__ W2, const float* __restrict__ b2,
    const float* __restrict__ g2, const float* __restrict__ be2,
    const float* __restrict__ Wa, const float* __restrict__ ba,
    const float* __restrict__ Wb, const float* __restrict__ bb,
    float* __restrict__ out) {
    __shared__ float W1s[4096], W2s[4096];
    int tid = threadIdx.x;
    for (int i = tid; i < 4096; i += 128) { W1s[i] = W1[i]; W2s[i] = W2[i]; }
    __syncthreads();
    int lane = tid & 63;
    int w = tid >> 6;
    int p = blockIdx.x * 2 + w;
    int a = __builtin_amdgcn_readfirstlane(pos[p]);
    int b = __builtin_amdgcn_readfirstlane(pos[Pq + p]);
    float ha = h2[a * 64 + lane], hb = h2[b * 64 + lane];
    float lb1 = b1[lane], lg1 = g1[lane], lbe1 = be1[lane];
    float lb2 = b2[lane], lg2 = g2[lane], lbe2 = be2[lane];
    float acc = 0.f;
    for (int wd = 0; wd < 16; ++wd) {
        ull bits = Mbit[a * 16 + wd] & MTbit[b * 16 + wd];
        while (bits) {
            int k = (wd << 6) + __ffsll(bits) - 1;
            bits &= bits - 1;
            float hk = h2[k * 64 + lane];
            float xeA = ha * hk;  // edge (a,k) -> head2 (x2, left operand)
            float xeB = hk * hb;  // edge (k,b) -> head1 (x1, right operand)
            float a2 = lb2, a1 = lb1;
            #pragma unroll 8
            for (int j = 0; j < 64; ++j) {
                float vA = __shfl(xeA, j);
                float vB = __shfl(xeB, j);
                a2 = fmaf(vA, W2s[j * 64 + lane], a2);
                a1 = fmaf(vB, W1s[j * 64 + lane], a1);
            }
            float s2 = a2, q2 = a2 * a2, s1 = a1, q1 = a1 * a1;
            for (int off = 32; off; off >>= 1) {
                s2 += __shfl_xor(s2, off); q2 += __shfl_xor(q2, off);
                s1 += __shfl_xor(s1, off); q1 += __shfl_xor(q1, off);
            }
            float mu2 = s2 * (1.f / 64.f), mu1 = s1 * (1.f / 64.f);
            float v2 = q2 * (1.f / 64.f) - mu2 * mu2;
            float v1 = q1 * (1.f / 64.f) - mu1 * mu1;
            float r2v = rsqrtf(v2 + 1e-5f), r1v = rsqrtf(v1 + 1e-5f);
            float x2v = fmaxf(0.f, (a2 - mu2) * r2v * lg2 + lbe2);
            float x1v = fmaxf(0.f, (a1 - mu1) * r1v * lg1 + lbe1);
            acc += x2v * x1v;
        }
    }
    float xx = ha * hb;
    // final MLP: hid = relu([acc, xx] @ Wa + ba); out = hid @ Wb + bb
    float t = ba[lane];
    #pragma unroll 8
    for (int j = 0; j < 64; ++j) {
        t = fmaf(__shfl(acc, j), Wa[j * 64 + lane], t);
        t = fmaf(__shfl(xx, j), Wa[(64 + j) * 64 + lane], t);
    }
    t = fmaxf(t, 0.f);
    float v = t * Wb[lane];
    for (int off = 32; off; off >>= 1) v += __shfl_xor(v, off);
    if (lane == 0) out[p] = v + bb[0];
}

extern "C" void kernel_launch(void* const* d_in, const int* in_sizes, int n_in,
                              void* d_out, int out_size, void* d_ws, size_t ws_size,
                              hipStream_t stream) {
    const float* x    = (const float*)d_in[0];
    const int*   ei   = (const int*)d_in[1];
    const int*   pos  = (const int*)d_in[2];
    const float* Wg1  = (const float*)d_in[3];
    const float* bg1  = (const float*)d_in[4];
    const float* Wg2  = (const float*)d_in[5];
    const float* bg2  = (const float*)d_in[6];
    const float* Wm1  = (const float*)d_in[7];
    const float* bm1  = (const float*)d_in[8];
    const float* gm1  = (const float*)d_in[9];
    const float* bem1 = (const float*)d_in[10];
    const float* Wm2  = (const float*)d_in[11];
    const float* bm2  = (const float*)d_in[12];
    const float* gm2  = (const float*)d_in[13];
    const float* bem2 = (const float*)d_in[14];
    const float* Wa   = (const float*)d_in[15];
    const float* ba   = (const float*)d_in[16];
    const float* Wb   = (const float*)d_in[17];
    const float* bb   = (const float*)d_in[18];
    float* out = (float*)d_out;

    char* w = (char*)d_ws;
    // --- zero-init region (one small memset) ---
    char* zbase = w;
    int* degI   = (int*)w;   w += 1024 * 4;
    int* cursor = (int*)w;   w += 1024 * 4;
    ull* Mbit   = (ull*)w;   w += 1024 * 16 * 8;
    ull* MTbit  = (ull*)w;   w += 1024 * 16 * 8;
    size_t zbytes = (size_t)(w - zbase);
    // --- no-init ---
    int*   dst_start = (int*)w;  w += 1024 * 4;
    float* dinv  = (float*)w;    w += 1024 * 4;
    int*   csr   = (int*)w;      w += Ee * 4;
    float* xw    = (float*)w;    w += 65536 * 4;
    float* h1    = (float*)w;    w += 65536 * 4;
    float* h2    = (float*)w;    w += 65536 * 4;

    hipMemsetAsync(zbase, 0, zbytes, stream);

    k_edgepass<<<Ee / 256, 256, 0, stream>>>(ei, degI, Mbit, MTbit);
    k_scan<<<1, 1024, 0, stream>>>(degI, dst_start, dinv);
    k_csr<<<Ee / 256, 256, 0, stream>>>(ei, dst_start, cursor, csr);

    // GCN layer 1
    k_xw<Din><<<Nn * 64 / 256, 256, 0, stream>>>(x, Wg1, xw);
    k_gather<<<Nn, 256, 0, stream>>>(csr, dst_start, degI, dinv, xw, bg1, h1);

    // GCN layer 2
    k_xw<Hh><<<Nn * 64 / 256, 256, 0, stream>>>(h1, Wg2, xw);
    k_gather<<<Nn, 256, 0, stream>>>(csr, dst_start, degI, dinv, xw, bg2, h2);

    // fused bilinear (on-the-fly edge MLPs) + xx + final MLP
    k_posfinal<<<Pq / 2, 128, 0, stream>>>(pos, Mbit, MTbit, h2,
                                           Wm1, bm1, gm1, bem1,
                                           Wm2, bm2, gm2, bem2,
                                           Wa, ba, Wb, bb, out);
}